// Round 1
// baseline (208.704 us; speedup 1.0000x reference)
//
#include <hip/hip_runtime.h>
#include <hip/hip_bf16.h>
#include <stdint.h>

// SelfAttention: B=8, C=64, N=4096, d_k=8.
// out[b,c,m] = gamma * (sum_n h[b,c,n] * softmax_n(f[:,n]. g[:,m])) + x[b,c,m]
//
// K1 (fgh_kernel): project x -> f_t (B,N,8) bf16 n-major, g_t (B,N,8) bf16
//     (pre-scaled by log2(e)), h (B,64,N) bf16 c-major. All in d_ws (5 MB).
// K2 (attn_kernel): flash-style, no-max softmax (|scores| ~ <=20, fp32 exp safe).
//     mfma_f32_32x32x8bf16_1k: S^T(32n x 32m) = Kfrag*Qfrag with K-dim=8 exact.
//     S^T C/D layout == PV A-operand layout (reg 4*ss+j <-> k=4h+j of subtile ss),
//     so exp + bf16-pack is pure in-register; no LDS roundtrip for P.
//     4 waves/block split n (4 x 1024); LDS-combine partials; fused epilogue.

typedef short v4s __attribute__((ext_vector_type(4)));
typedef float v16f __attribute__((ext_vector_type(16)));
typedef unsigned int v2u __attribute__((ext_vector_type(2)));

__device__ __forceinline__ unsigned short bf16r(float x) {
    unsigned u = __builtin_bit_cast(unsigned, x);
    return (unsigned short)((u + 0x8000u) >> 16);   // round-to-nearest-ish
}

// pack 4 fp32 -> 4 bf16 (truncation; P>=0 and feeds gamma-scaled path, fine)
__device__ __forceinline__ v4s pack4(float a, float b, float c, float d) {
    unsigned ua = __builtin_bit_cast(unsigned, a);
    unsigned ub = __builtin_bit_cast(unsigned, b);
    unsigned uc = __builtin_bit_cast(unsigned, c);
    unsigned ud = __builtin_bit_cast(unsigned, d);
    v2u r;
    r.x = (ua >> 16) | (ub & 0xffff0000u);
    r.y = (uc >> 16) | (ud & 0xffff0000u);
    return __builtin_bit_cast(v4s, r);
}

// ---------------- K1: projections ----------------
// 5 o-groups per (b,n): og0 -> f[8]+g[8], og1..4 -> h rows 16(og-1)..16og
__global__ __launch_bounds__(256) void fgh_kernel(
    const float* __restrict__ x, const float* __restrict__ Wq,
    const float* __restrict__ Wk, const float* __restrict__ Wv,
    unsigned short* __restrict__ ft, unsigned short* __restrict__ gt,
    unsigned short* __restrict__ hw)
{
    int gid = blockIdx.x * 256 + threadIdx.x;   // 5*8*4096 = 163840 threads
    int og  = gid >> 15;                        // /32768 (wave-uniform)
    int rem = gid & 32767;
    int b   = rem >> 12;
    int n   = rem & 4095;

    const float* xp = x + (size_t)b * 64 * 4096 + n;
    float xc[64];
    #pragma unroll
    for (int c = 0; c < 64; ++c) xc[c] = xp[(size_t)c * 4096];

    if (og == 0) {
        unsigned short fo[8], go[8];
        #pragma unroll
        for (int o = 0; o < 8; ++o) {
            float af = 0.f, ag = 0.f;
            #pragma unroll
            for (int c = 0; c < 64; ++c) {
                af += Wq[o * 64 + c] * xc[c];
                ag += Wk[o * 64 + c] * xc[c];
            }
            ag *= 1.4426950408889634f;          // fold log2(e): hot loop uses exp2
            fo[o] = bf16r(af);
            go[o] = bf16r(ag);
        }
        size_t row = ((size_t)b * 4096 + n) * 8;
        #pragma unroll
        for (int o = 0; o < 8; ++o) { ft[row + o] = fo[o]; gt[row + o] = go[o]; }
    } else {
        int c0 = (og - 1) << 4;
        #pragma unroll
        for (int r = 0; r < 16; ++r) {
            float a = 0.f;
            #pragma unroll
            for (int c = 0; c < 64; ++c) a += Wv[(c0 + r) * 64 + c] * xc[c];
            hw[((size_t)b * 64 + c0 + r) * 4096 + n] = bf16r(a);
        }
    }
}

// ---------------- K2: fused attention ----------------
// grid 1024: b = blk>>7, m0 = (blk&127)*32. 4 waves split n into 1024-chunks.
__global__ __launch_bounds__(256, 4) void attn_kernel(
    const unsigned short* __restrict__ ft,
    const unsigned short* __restrict__ gt,
    const unsigned short* __restrict__ hw,
    const float* __restrict__ x,
    const float* __restrict__ gamma,
    float* __restrict__ out)
{
    __shared__ float ldsO[4][32][65];   // +1 pad: conflict-free write(c-contig)/read(m-contig)
    __shared__ float ldsL[4][32];

    const int blk  = blockIdx.x;
    const int b    = blk >> 7;
    const int m0   = (blk & 127) << 5;
    const int tid  = threadIdx.x;
    const int wave = tid >> 6;
    const int lane = tid & 63;
    const int l5   = lane & 31;
    const int hh   = lane >> 5;

    const v4s* ft4 = (const v4s*)ft;
    const v4s* gt4 = (const v4s*)gt;

    // Q B-frag: B[k=c][col=m]: lane holds m=l5, c=4*hh..4*hh+3. Loaded once.
    v4s qf = gt4[((size_t)b * 4096 + m0 + l5) * 2 + hh];

    v16f acc0 = {0.f,0.f,0.f,0.f,0.f,0.f,0.f,0.f,0.f,0.f,0.f,0.f,0.f,0.f,0.f,0.f};
    v16f acc1 = acc0;
    float lsum = 0.f;

    const unsigned short* vb0 = hw + ((size_t)b * 64 + l5) * 4096;        // c-tile 0
    const unsigned short* vb1 = hw + ((size_t)b * 64 + 32 + l5) * 4096;   // c-tile 1

    const int nbase = wave << 10;
    for (int it = 0; it < 32; ++it) {
        const int n0 = nbase + (it << 5);

        // K A-frag: A[row=n][k=c]: lane holds n=n0+l5, c=4*hh..4*hh+3
        v4s kf = ft4[((size_t)b * 4096 + n0 + l5) * 2 + hh];

        v16f s = {0.f,0.f,0.f,0.f,0.f,0.f,0.f,0.f,0.f,0.f,0.f,0.f,0.f,0.f,0.f,0.f};
        s = __builtin_amdgcn_mfma_f32_32x32x8bf16_1k(kf, qf, s, 0, 0, 0);
        // s[reg] = S^T[n=(reg&3)+8*(reg>>2)+4*hh][m=l5]  (log2-domain scores)

        float p[16];
        #pragma unroll
        for (int j = 0; j < 16; ++j) p[j] = __builtin_amdgcn_exp2f(s[j]);
        #pragma unroll
        for (int j = 0; j < 16; ++j) lsum += p[j];

        #pragma unroll
        for (int ss = 0; ss < 4; ++ss) {
            // PV A-frag for n-subtile ss: A[m=l5][k=4*hh+j] = p[4*ss+j] -- identity!
            v4s pf = pack4(p[4*ss], p[4*ss+1], p[4*ss+2], p[4*ss+3]);
            // V B-frag: B[k=n][col=c]: lane c=l5(+32), n = n0+8*ss+4*hh..+3
            v4s v0 = *(const v4s*)(vb0 + n0 + ss * 8 + 4 * hh);
            v4s v1 = *(const v4s*)(vb1 + n0 + ss * 8 + 4 * hh);
            acc0 = __builtin_amdgcn_mfma_f32_32x32x8bf16_1k(pf, v0, acc0, 0, 0, 0);
            acc1 = __builtin_amdgcn_mfma_f32_32x32x8bf16_1k(pf, v1, acc1, 0, 0, 0);
        }
    }

    // l: lanes l and l+32 hold the same m=l5 (disjoint n) -> fold halves
    lsum += __shfl_xor(lsum, 32);
    if (hh == 0) ldsL[wave][l5] = lsum;

    // O C/D: col c=l5(+32), row m=(reg&3)+8*(reg>>2)+4*hh
    #pragma unroll
    for (int r = 0; r < 16; ++r) {
        int m = (r & 3) + ((r >> 2) << 3) + (hh << 2);
        ldsO[wave][m][l5]      = acc0[r];
        ldsO[wave][m][32 + l5] = acc1[r];
    }
    __syncthreads();

    // combine 4 waves + normalize + gamma*o + x, coalesced over m
    const float gam = gamma[0];
    const int m  = tid & 31;
    const int cg = tid >> 5;
    const float L = ldsL[0][m] + ldsL[1][m] + ldsL[2][m] + ldsL[3][m];
    const float rL = 1.0f / L;
    #pragma unroll
    for (int k = 0; k < 8; ++k) {
        int c = cg * 8 + k;
        float O = ldsO[0][m][c] + ldsO[1][m][c] + ldsO[2][m][c] + ldsO[3][m][c];
        size_t idx = ((size_t)b * 64 + c) * 4096 + m0 + m;
        out[idx] = gam * (O * rL) + x[idx];
    }
}

extern "C" void kernel_launch(void* const* d_in, const int* in_sizes, int n_in,
                              void* d_out, int out_size, void* d_ws, size_t ws_size,
                              hipStream_t stream) {
    const float* x     = (const float*)d_in[0];
    const float* Wq    = (const float*)d_in[1];
    const float* Wk    = (const float*)d_in[2];
    const float* Wv    = (const float*)d_in[3];
    const float* gamma = (const float*)d_in[4];
    float* out = (float*)d_out;

    unsigned short* ft = (unsigned short*)d_ws;          // 8*4096*8 bf16 = 512 KB
    unsigned short* gt = ft + 8 * 4096 * 8;              // 512 KB
    unsigned short* hw = gt + 8 * 4096 * 8;              // 8*64*4096 bf16 = 4 MB

    hipLaunchKernelGGL(fgh_kernel, dim3(640), dim3(256), 0, stream,
                       x, Wq, Wk, Wv, ft, gt, hw);
    hipLaunchKernelGGL(attn_kernel, dim3(1024), dim3(256), 0, stream,
                       ft, gt, hw, x, gamma, out);
}

// Round 2
// 113.992 us; speedup vs baseline: 1.8309x; 1.8309x over previous
//
#include <hip/hip_runtime.h>
#include <hip/hip_bf16.h>
#include <stdint.h>

// SelfAttention: B=8, C=64, N=4096, d_k=8.
// out[b,c,m] = gamma * (sum_n h[b,c,n] * softmax_n(f[:,n].g[:,m])) + x[b,c,m]
//
// K1 (fgh): x -> ft (B,N,8) bf16, gt (B,N,8) bf16 (pre-scaled log2e),
//           hswz = h in MFMA-B-fragment-swizzled order so K2's V loads are
//           single coalesced dwordx4 per (n-tile, ss).
//           hswz byte addr = (b*128+nb)*4096 + ss*1024 + (l5+32*hh)*16 + ct*8 + j*2
//           holding h[b][c=ct*32+l5][n=nb*32+ss*8+4*hh+j].
// K2 (attn): flash-style no-max softmax (|s|<~20 fp32-safe).
//           mfma_f32_32x32x8bf16_1k: S^T C/D layout == PV A-operand layout ->
//           exp+pack fully in-register. 4 waves split n; prefetched V/K loads.

typedef short v4s __attribute__((ext_vector_type(4)));
typedef float v16f __attribute__((ext_vector_type(16)));
typedef unsigned int v4u __attribute__((ext_vector_type(4)));
typedef unsigned int v2u __attribute__((ext_vector_type(2)));

__device__ __forceinline__ unsigned bf16pair(float lo, float hi) {
    unsigned a = __builtin_bit_cast(unsigned, lo) + 0x8000u;
    unsigned b = __builtin_bit_cast(unsigned, hi) + 0x8000u;
    return (a >> 16) | (b & 0xffff0000u);
}

__device__ __forceinline__ v4s pack4(float a, float b, float c, float d) {
    v2u r;
    r.x = bf16pair(a, b);
    r.y = bf16pair(c, d);
    return __builtin_bit_cast(v4s, r);
}

// ---------------- K1: projections ----------------
// block = (b, og, nt): og0 -> f rows 0..7 (Wq), og1 -> g rows 0..7 (Wk, *log2e),
// og2..9 -> h rows (og-2)*8 .. +7 (Wv). Thread owns 4 consecutive n.
__global__ __launch_bounds__(256) void fgh_kernel(
    const float* __restrict__ x, const float* __restrict__ Wq,
    const float* __restrict__ Wk, const float* __restrict__ Wv,
    unsigned int* __restrict__ ftgt,   // ft at 0, gt at +65536 dwords
    unsigned int* __restrict__ hswz)
{
    const int blk = blockIdx.x;           // 8*10*4 = 320
    const int nt  = blk & 3;
    const int og  = (blk >> 2) % 10;
    const int b   = (blk >> 2) / 10;
    const int n   = (nt * 256 + threadIdx.x) * 4;

    const float* xb = x + (size_t)b * 64 * 4096 + n;

    const float* W = (og == 0) ? Wq : (og == 1) ? Wk : (Wv + (og - 2) * 8 * 64);

    float4 acc[8];
    #pragma unroll
    for (int r = 0; r < 8; ++r) acc[r] = make_float4(0.f, 0.f, 0.f, 0.f);

    for (int cc = 0; cc < 64; cc += 8) {
        float4 xv[8];
        #pragma unroll
        for (int j = 0; j < 8; ++j)
            xv[j] = *(const float4*)(xb + (size_t)(cc + j) * 4096);
        #pragma unroll
        for (int r = 0; r < 8; ++r) {
            #pragma unroll
            for (int j = 0; j < 8; ++j) {
                const float w = W[r * 64 + cc + j];   // uniform -> s_load
                acc[r].x += w * xv[j].x;
                acc[r].y += w * xv[j].y;
                acc[r].z += w * xv[j].z;
                acc[r].w += w * xv[j].w;
            }
        }
    }

    if (og < 2) {
        const float scale = (og == 0) ? 1.0f : 1.4426950408889634f;
        #pragma unroll
        for (int r = 0; r < 8; ++r) {
            acc[r].x *= scale; acc[r].y *= scale;
            acc[r].z *= scale; acc[r].w *= scale;
        }
        // layout [b][n][8 o] bf16: thread region = 64 contiguous bytes
        unsigned int* dst = ftgt + (size_t)og * 65536 + ((size_t)b * 4096 + n) * 4;
        #pragma unroll
        for (int k = 0; k < 4; ++k) {           // per n+k: 8 o = 4 dwords
            v4u d;
            d.x = bf16pair(((const float*)&acc[0])[k], ((const float*)&acc[1])[k]);
            d.y = bf16pair(((const float*)&acc[2])[k], ((const float*)&acc[3])[k]);
            d.z = bf16pair(((const float*)&acc[4])[k], ((const float*)&acc[5])[k]);
            d.w = bf16pair(((const float*)&acc[6])[k], ((const float*)&acc[7])[k]);
            *(v4u*)(dst + (size_t)k * 4) = d;
        }
    } else {
        const int r0   = (og - 2) * 8;
        const int nb   = n >> 5;
        const int nloc = n & 31;
        const int ss   = nloc >> 3;
        const int hh   = (nloc >> 2) & 1;
        char* base = (char*)hswz + ((size_t)(b * 128 + nb)) * 4096
                   + ss * 1024 + hh * 512;      // + l5*16 + ct*8
        #pragma unroll
        for (int r = 0; r < 8; ++r) {
            const int c  = r0 + r;
            const int l5 = c & 31;
            const int ct = c >> 5;
            v2u d;
            d.x = bf16pair(acc[r].x, acc[r].y);
            d.y = bf16pair(acc[r].z, acc[r].w);
            *(v2u*)(base + l5 * 16 + ct * 8) = d;
        }
    }
}

// ---------------- K2: fused attention ----------------
__global__ __launch_bounds__(256, 4) void attn_kernel(
    const v4s* __restrict__ ft4,      // [b][n][2 halves of 8 bf16]
    const v4s* __restrict__ gt4,
    const char* __restrict__ hswz,
    const float* __restrict__ x,
    const float* __restrict__ gamma,
    float* __restrict__ out)
{
    __shared__ float ldsO[4][32][65];
    __shared__ float ldsL[4][32];

    const int blk  = blockIdx.x;
    const int b    = blk >> 7;
    const int m0   = (blk & 127) << 5;
    const int tid  = threadIdx.x;
    const int wave = tid >> 6;
    const int lane = tid & 63;
    const int l5   = lane & 31;
    const int hh   = lane >> 5;

    // Q B-frag: lane holds m=m0+l5, c=4*hh..+3
    const v4s qf = gt4[((size_t)b * 4096 + m0 + l5) * 2 + hh];

    v16f acc0 = {0.f,0.f,0.f,0.f,0.f,0.f,0.f,0.f,0.f,0.f,0.f,0.f,0.f,0.f,0.f,0.f};
    v16f acc1 = acc0;
    float lsum = 0.f;

    const char* vb = hswz + ((size_t)b * 128) * 4096 + lane * 16;
    const int nbase = wave << 10;

    // prefetch iter 0
    v4s kf_n = ft4[((size_t)b * 4096 + nbase + l5) * 2 + hh];
    v4u vv_n[4];
    #pragma unroll
    for (int ss = 0; ss < 4; ++ss)
        vv_n[ss] = *(const v4u*)(vb + (size_t)(nbase >> 5) * 4096 + ss * 1024);

    for (int it = 0; it < 32; ++it) {
        const v4s kf = kf_n;
        v4u vv[4];
        #pragma unroll
        for (int ss = 0; ss < 4; ++ss) vv[ss] = vv_n[ss];

        // prefetch next (wraps to iter 0 on last -- always valid, never used)
        const int itn = (it + 1) & 31;
        const int n0n = nbase + (itn << 5);
        kf_n = ft4[((size_t)b * 4096 + n0n + l5) * 2 + hh];
        #pragma unroll
        for (int ss = 0; ss < 4; ++ss)
            vv_n[ss] = *(const v4u*)(vb + (size_t)(n0n >> 5) * 4096 + ss * 1024);

        v16f s = {0.f,0.f,0.f,0.f,0.f,0.f,0.f,0.f,0.f,0.f,0.f,0.f,0.f,0.f,0.f,0.f};
        s = __builtin_amdgcn_mfma_f32_32x32x8bf16_1k(kf, qf, s, 0, 0, 0);
        // s[reg] = S^T[n=(reg&3)+8*(reg>>2)+4*hh][m=m0+l5] in log2 domain

        float p[16];
        #pragma unroll
        for (int j = 0; j < 16; ++j) p[j] = __builtin_amdgcn_exp2f(s[j]);
        #pragma unroll
        for (int j = 0; j < 16; ++j) lsum += p[j];

        #pragma unroll
        for (int ss = 0; ss < 4; ++ss) {
            const v4s pf = pack4(p[4*ss], p[4*ss+1], p[4*ss+2], p[4*ss+3]);
            v2u lo; lo.x = vv[ss].x; lo.y = vv[ss].y;
            v2u hi; hi.x = vv[ss].z; hi.y = vv[ss].w;
            const v4s v0 = __builtin_bit_cast(v4s, lo);   // c-tile 0 frag
            const v4s v1 = __builtin_bit_cast(v4s, hi);   // c-tile 1 frag
            acc0 = __builtin_amdgcn_mfma_f32_32x32x8bf16_1k(pf, v0, acc0, 0, 0, 0);
            acc1 = __builtin_amdgcn_mfma_f32_32x32x8bf16_1k(pf, v1, acc1, 0, 0, 0);
        }
    }

    lsum += __shfl_xor(lsum, 32);
    if (hh == 0) ldsL[wave][l5] = lsum;

    #pragma unroll
    for (int r = 0; r < 16; ++r) {
        const int m = (r & 3) + ((r >> 2) << 3) + (hh << 2);
        ldsO[wave][m][l5]      = acc0[r];
        ldsO[wave][m][32 + l5] = acc1[r];
    }
    __syncthreads();

    const float gam = gamma[0];
    const int m  = tid & 31;
    const int cg = tid >> 5;
    const float L = ldsL[0][m] + ldsL[1][m] + ldsL[2][m] + ldsL[3][m];
    const float rL = 1.0f / L;
    #pragma unroll
    for (int k = 0; k < 8; ++k) {
        const int c = cg * 8 + k;
        const float O = ldsO[0][m][c] + ldsO[1][m][c] + ldsO[2][m][c] + ldsO[3][m][c];
        const size_t idx = ((size_t)b * 64 + c) * 4096 + m0 + m;
        out[idx] = gam * (O * rL) + x[idx];
    }
}

extern "C" void kernel_launch(void* const* d_in, const int* in_sizes, int n_in,
                              void* d_out, int out_size, void* d_ws, size_t ws_size,
                              hipStream_t stream) {
    const float* x     = (const float*)d_in[0];
    const float* Wq    = (const float*)d_in[1];
    const float* Wk    = (const float*)d_in[2];
    const float* Wv    = (const float*)d_in[3];
    const float* gamma = (const float*)d_in[4];
    float* out = (float*)d_out;

    unsigned int* ftgt = (unsigned int*)d_ws;            // ft 512KB + gt 512KB
    unsigned int* hswz = ftgt + 2 * 65536;               // 4MB swizzled h

    hipLaunchKernelGGL(fgh_kernel, dim3(320), dim3(256), 0, stream,
                       x, Wq, Wk, Wv, ftgt, hswz);
    hipLaunchKernelGGL(attn_kernel, dim3(1024), dim3(256), 0, stream,
                       (const v4s*)ftgt, (const v4s*)(ftgt + 65536),
                       (const char*)hswz, x, gamma, out);
}

// Round 3
// 105.426 us; speedup vs baseline: 1.9796x; 1.0812x over previous
//
#include <hip/hip_runtime.h>
#include <hip/hip_bf16.h>
#include <stdint.h>

// SelfAttention: B=8, C=64, N=4096, d_k=8.
// out[b,c,m] = gamma * (sum_n h[b,c,n] * softmax_n(f[:,n].g[:,m])) + x[b,c,m]
//
// K1 (fgh): MFMA projection, x read ONCE. Per (b, 32-n tile) block:
//   stage all 80 W rows (Wv 64 + Wq 8 + Wk 8, Wk pre-scaled log2e) as
//   A-fragment-ordered bf16 in LDS, x-tile as B-fragment-ordered bf16 in LDS,
//   3 waves x 8 mfma(32x32x8) steps -> all 80 outputs. Epilogue scatters:
//   f/g direct coalesced dwordx2; h via LDS transpose -> hswz dwordx4.
//   hswz layout: [(b*128+nb)*4096B] + ss*1024 + hh*512 + l5*16 + ct*8 + j*2
//   holding h[b][c=ct*32+l5][n=nb*32+ss*8+4*hh+j] (= attn V B-fragment order).
// K2 (attn): flash-style no-max softmax (|s|<~20, fp32 exp2 safe).
//   64 m per block (2 m-tiles per wave), 4 waves split n (4x1024).
//   S^T C/D layout == PV A-operand layout -> exp+pack fully in-register.
//   2-copy LDS phase-add combine (33 KB) keeps ~3 waves/SIMD.

typedef short v4s __attribute__((ext_vector_type(4)));
typedef float v16f __attribute__((ext_vector_type(16)));
typedef unsigned int v4u __attribute__((ext_vector_type(4)));
typedef unsigned int v2u __attribute__((ext_vector_type(2)));

__device__ __forceinline__ unsigned bf16pair(float lo, float hi) {
    unsigned a = __builtin_bit_cast(unsigned, lo) + 0x8000u;
    unsigned b = __builtin_bit_cast(unsigned, hi) + 0x8000u;
    return (a >> 16) | (b & 0xffff0000u);
}
__device__ __forceinline__ unsigned short bf16r(float x) {
    return (unsigned short)((__builtin_bit_cast(unsigned, x) + 0x8000u) >> 16);
}
__device__ __forceinline__ v4s pack4(float a, float b, float c, float d) {
    v2u r; r.x = bf16pair(a, b); r.y = bf16pair(c, d);
    return __builtin_bit_cast(v4s, r);
}

// ---------------- K1: MFMA projection ----------------
// grid 1024 = (b<<7)|nb. Wave w<2: h rows w*32..+31; wave 2: f(0-7)+g(8-15).
__global__ __launch_bounds__(256) void fgh_kernel(
    const float* __restrict__ x, const float* __restrict__ Wq,
    const float* __restrict__ Wk, const float* __restrict__ Wv,
    unsigned int* __restrict__ ftgt,   // ft dwords [0,131072), gt [131072,262144)
    v4u* __restrict__ hswz)
{
    __shared__ v2u wfrag[1536];        // 3 row-groups x 8 kb x 64 lanes x 8B
    __shared__ v2u xfrag[512];         // 8 kb x 64 lanes x 8B
    __shared__ short hbuf[64 * 36];    // [c][nloc] pad 36 vs 32

    const int blk  = blockIdx.x;
    const int b    = blk >> 7;
    const int nb   = blk & 127;
    const int n0   = nb << 5;
    const int tid  = threadIdx.x;
    const int wave = tid >> 6;
    const int lane = tid & 63;
    const int l5   = lane & 31;
    const int hh   = lane >> 5;

    const float* xb = x + (size_t)b * 262144 + n0;

    // stage W fragments: A[row][k=kb*8+4*hf+j]
    #pragma unroll
    for (int i = 0; i < 6; ++i) {
        const int e  = tid + i * 256;
        const int w  = e >> 9;
        const int kb = (e >> 6) & 7;
        const int r  = e & 31;
        const int hf = (e >> 5) & 1;
        const int k0 = kb * 8 + hf * 4;
        float4 wv = make_float4(0.f, 0.f, 0.f, 0.f);
        if (w == 0)      wv = *(const float4*)(Wv + r * 64 + k0);
        else if (w == 1) wv = *(const float4*)(Wv + (32 + r) * 64 + k0);
        else if (r < 8)  wv = *(const float4*)(Wq + r * 64 + k0);
        else if (r < 16) {
            wv = *(const float4*)(Wk + (r - 8) * 64 + k0);
            const float s = 1.4426950408889634f;   // fold log2(e) into g
            wv.x *= s; wv.y *= s; wv.z *= s; wv.w *= s;
        }
        v2u d; d.x = bf16pair(wv.x, wv.y); d.y = bf16pair(wv.z, wv.w);
        wfrag[e] = d;
    }

    // stage x fragments: B[col=n][k=c], coalesced dword runs over n
    #pragma unroll
    for (int i = 0; i < 2; ++i) {
        const int e  = tid + i * 256;
        const int kb = e >> 6;
        const int nn = e & 31;
        const int hf = (e >> 5) & 1;
        const int c0 = kb * 8 + hf * 4;
        const float a0 = xb[(size_t)(c0 + 0) * 4096 + nn];
        const float a1 = xb[(size_t)(c0 + 1) * 4096 + nn];
        const float a2 = xb[(size_t)(c0 + 2) * 4096 + nn];
        const float a3 = xb[(size_t)(c0 + 3) * 4096 + nn];
        v2u d; d.x = bf16pair(a0, a1); d.y = bf16pair(a2, a3);
        xfrag[e] = d;
    }
    __syncthreads();

    if (wave < 3) {
        v16f dacc = {0.f,0.f,0.f,0.f,0.f,0.f,0.f,0.f,0.f,0.f,0.f,0.f,0.f,0.f,0.f,0.f};
        #pragma unroll
        for (int kb = 0; kb < 8; ++kb) {
            const v4s af = __builtin_bit_cast(v4s, wfrag[wave * 512 + kb * 64 + lane]);
            const v4s bf = __builtin_bit_cast(v4s, xfrag[kb * 64 + lane]);
            dacc = __builtin_amdgcn_mfma_f32_32x32x8bf16_1k(af, bf, dacc, 0, 0, 0);
        }
        // D: row=(r&3)+8*(r>>2)+4*hh, col=n0+l5
        if (wave < 2) {
            #pragma unroll
            for (int r = 0; r < 16; ++r) {
                const int rowD = (r & 3) + ((r >> 2) << 3) + (hh << 2);
                hbuf[(wave * 32 + rowD) * 36 + l5] = (short)bf16r(dacc[r]);
            }
        } else {
            // rows 0-7 = f (o=(r&3)+4hh, regs 0-3), rows 8-15 = g (regs 4-7)
            const size_t nidx = (size_t)b * 4096 + n0 + l5;
            v2u f; f.x = bf16pair(dacc[0], dacc[1]); f.y = bf16pair(dacc[2], dacc[3]);
            v2u g; g.x = bf16pair(dacc[4], dacc[5]); g.y = bf16pair(dacc[6], dacc[7]);
            *(v2u*)(ftgt + nidx * 4 + hh * 2) = f;
            *(v2u*)(ftgt + 131072 + nidx * 4 + hh * 2) = g;
        }
    }
    __syncthreads();

    // assemble hswz: thread t emits 16 contiguous bytes
    const int ss  = tid >> 6;
    const int h2  = (tid >> 5) & 1;
    const int lp  = tid & 31;
    const int nl0 = ss * 8 + h2 * 4;
    const v2u lo = *(const v2u*)(hbuf + lp * 36 + nl0);          // ct=0
    const v2u hi = *(const v2u*)(hbuf + (32 + lp) * 36 + nl0);   // ct=1
    v4u o; o.x = lo.x; o.y = lo.y; o.z = hi.x; o.w = hi.y;
    hswz[(size_t)(b * 128 + nb) * 256 + tid] = o;
}

// ---------------- K2: fused attention ----------------
// grid 512 = (b<<6)|mb, m0 = mb*64. Each wave: both m-tiles, n-quarter.
__global__ __launch_bounds__(256, 3) void attn_kernel(
    const v4s* __restrict__ ft4,
    const v4s* __restrict__ gt4,
    const char* __restrict__ hswz,
    const float* __restrict__ x,
    const float* __restrict__ gamma,
    float* __restrict__ out)
{
    __shared__ float ldsO[2][64 * 65];
    __shared__ float ldsL[2][64];

    const int blk  = blockIdx.x;
    const int b    = blk >> 6;
    const int m0   = (blk & 63) << 6;
    const int tid  = threadIdx.x;
    const int wave = tid >> 6;
    const int lane = tid & 63;
    const int l5   = lane & 31;
    const int hh   = lane >> 5;

    // Q B-frags for both m-tiles: lane holds m, c=4*hh..+3
    const v4s qf0 = gt4[((size_t)b * 4096 + m0 + l5) * 2 + hh];
    const v4s qf1 = gt4[((size_t)b * 4096 + m0 + 32 + l5) * 2 + hh];

    v16f acc00 = {0.f,0.f,0.f,0.f,0.f,0.f,0.f,0.f,0.f,0.f,0.f,0.f,0.f,0.f,0.f,0.f};
    v16f acc01 = acc00, acc10 = acc00, acc11 = acc00;
    float lsum0 = 0.f, lsum1 = 0.f;

    const char* vb = hswz + (size_t)b * 524288 + lane * 16;
    const int nbase = wave << 10;

    // prefetch iter 0
    v4s kf_n = ft4[((size_t)b * 4096 + nbase + l5) * 2 + hh];
    v4u vv_n[4];
    #pragma unroll
    for (int ss = 0; ss < 4; ++ss)
        vv_n[ss] = *(const v4u*)(vb + (size_t)(nbase >> 5) * 4096 + ss * 1024);

    for (int it = 0; it < 32; ++it) {
        const v4s kf = kf_n;
        v4u vv[4];
        #pragma unroll
        for (int ss = 0; ss < 4; ++ss) vv[ss] = vv_n[ss];

        const int itn = (it + 1) & 31;            // wrap: valid, unused
        const int n0n = nbase + (itn << 5);
        kf_n = ft4[((size_t)b * 4096 + n0n + l5) * 2 + hh];
        #pragma unroll
        for (int ss = 0; ss < 4; ++ss)
            vv_n[ss] = *(const v4u*)(vb + (size_t)(n0n >> 5) * 4096 + ss * 1024);

        v16f z = {0.f,0.f,0.f,0.f,0.f,0.f,0.f,0.f,0.f,0.f,0.f,0.f,0.f,0.f,0.f,0.f};
        v16f s0 = __builtin_amdgcn_mfma_f32_32x32x8bf16_1k(kf, qf0, z, 0, 0, 0);
        v16f s1 = __builtin_amdgcn_mfma_f32_32x32x8bf16_1k(kf, qf1, z, 0, 0, 0);
        // s[reg] = S^T[n=(reg&3)+8*(reg>>2)+4hh][m] in log2 domain

        #pragma unroll
        for (int ss = 0; ss < 4; ++ss) {
            float p0[4], p1[4];
            #pragma unroll
            for (int j = 0; j < 4; ++j) {
                p0[j] = __builtin_amdgcn_exp2f(s0[4 * ss + j]);
                p1[j] = __builtin_amdgcn_exp2f(s1[4 * ss + j]);
            }
            lsum0 += (p0[0] + p0[1]) + (p0[2] + p0[3]);
            lsum1 += (p1[0] + p1[1]) + (p1[2] + p1[3]);
            const v4s pf0 = pack4(p0[0], p0[1], p0[2], p0[3]);
            const v4s pf1 = pack4(p1[0], p1[1], p1[2], p1[3]);
            v2u lo; lo.x = vv[ss].x; lo.y = vv[ss].y;
            v2u hi; hi.x = vv[ss].z; hi.y = vv[ss].w;
            const v4s v0 = __builtin_bit_cast(v4s, lo);   // c 0-31 frag
            const v4s v1 = __builtin_bit_cast(v4s, hi);   // c 32-63 frag
            acc00 = __builtin_amdgcn_mfma_f32_32x32x8bf16_1k(pf0, v0, acc00, 0, 0, 0);
            acc01 = __builtin_amdgcn_mfma_f32_32x32x8bf16_1k(pf0, v1, acc01, 0, 0, 0);
            acc10 = __builtin_amdgcn_mfma_f32_32x32x8bf16_1k(pf1, v0, acc10, 0, 0, 0);
            acc11 = __builtin_amdgcn_mfma_f32_32x32x8bf16_1k(pf1, v1, acc11, 0, 0, 0);
        }
    }

    // fold lane/lane+32 (same m, disjoint n)
    lsum0 += __shfl_xor(lsum0, 32);
    lsum1 += __shfl_xor(lsum1, 32);

    // 2-copy phase-add combine: waves 0,1 write; waves 2,3 add.
    if (wave < 2) {
        float* P = &ldsO[wave][0];
        #pragma unroll
        for (int r = 0; r < 16; ++r) {
            const int rowD = (r & 3) + ((r >> 2) << 3) + (hh << 2);
            P[rowD * 65 + l5]             = acc00[r];
            P[rowD * 65 + 32 + l5]        = acc01[r];
            P[(32 + rowD) * 65 + l5]      = acc10[r];
            P[(32 + rowD) * 65 + 32 + l5] = acc11[r];
        }
        if (hh == 0) { ldsL[wave][l5] = lsum0; ldsL[wave][32 + l5] = lsum1; }
    }
    __syncthreads();
    if (wave >= 2) {
        float* P = &ldsO[wave - 2][0];
        #pragma unroll
        for (int r = 0; r < 16; ++r) {
            const int rowD = (r & 3) + ((r >> 2) << 3) + (hh << 2);
            P[rowD * 65 + l5]             += acc00[r];
            P[rowD * 65 + 32 + l5]        += acc01[r];
            P[(32 + rowD) * 65 + l5]      += acc10[r];
            P[(32 + rowD) * 65 + 32 + l5] += acc11[r];
        }
        if (hh == 0) { ldsL[wave - 2][l5] += lsum0; ldsL[wave - 2][32 + l5] += lsum1; }
    }
    __syncthreads();

    // final: normalize + gamma*o + x, coalesced over m
    const float gam = gamma[0];
    const int m  = tid & 63;
    const int c0 = (tid >> 6) * 16;
    const float L = ldsL[0][m] + ldsL[1][m];
    const float rL = 1.0f / L;
    #pragma unroll
    for (int k = 0; k < 16; ++k) {
        const int c = c0 + k;
        const float O = ldsO[0][m * 65 + c] + ldsO[1][m * 65 + c];
        const size_t idx = ((size_t)b * 64 + c) * 4096 + m0 + m;
        out[idx] = gam * (O * rL) + x[idx];
    }
}

extern "C" void kernel_launch(void* const* d_in, const int* in_sizes, int n_in,
                              void* d_out, int out_size, void* d_ws, size_t ws_size,
                              hipStream_t stream) {
    const float* x     = (const float*)d_in[0];
    const float* Wq    = (const float*)d_in[1];
    const float* Wk    = (const float*)d_in[2];
    const float* Wv    = (const float*)d_in[3];
    const float* gamma = (const float*)d_in[4];
    float* out = (float*)d_out;

    unsigned int* ftgt = (unsigned int*)d_ws;   // ft 512KB + gt 512KB (disjoint!)
    v4u* hswz = (v4u*)(ftgt + 262144);          // 4MB fragment-swizzled h

    hipLaunchKernelGGL(fgh_kernel, dim3(1024), dim3(256), 0, stream,
                       x, Wq, Wk, Wv, ftgt, hswz);
    hipLaunchKernelGGL(attn_kernel, dim3(512), dim3(256), 0, stream,
                       (const v4s*)ftgt, (const v4s*)(ftgt + 131072),
                       (const char*)hswz, x, gamma, out);
}